// Round 1
// baseline (1214.234 us; speedup 1.0000x reference)
//
#include <hip/hip_runtime.h>

#define Bn 16
#define Sn 2048
#define Hn 1024

typedef float floatx4 __attribute__((ext_vector_type(4)));
typedef __bf16 bf16x8 __attribute__((ext_vector_type(8)));
typedef unsigned short ushort8v __attribute__((ext_vector_type(8)));

__device__ __forceinline__ unsigned short f2bf(float f) {
  unsigned u = __builtin_bit_cast(unsigned, f);
  u += 0x7FFFu + ((u >> 16) & 1u);  // RNE
  return (unsigned short)(u >> 16);
}
__device__ __forceinline__ float bf2f(unsigned short h) {
  unsigned u = ((unsigned)h) << 16;
  return __builtin_bit_cast(float, u);
}

__device__ __forceinline__ void async16(const unsigned short* g, unsigned short* l) {
  typedef __attribute__((address_space(1))) const unsigned char gu8;
  typedef __attribute__((address_space(3))) unsigned char lu8;
  __builtin_amdgcn_global_load_lds((gu8*)g, (lu8*)l, 16, 0, 0);
}

// ---- bf16 NT GEMM mainloop: C(128x128) = A(128xK) * B(128xK)^T ----
// LDS layout [row][32] bf16, staged with global_load_lds width 16.
__device__ __forceinline__ void gemm_bt_main(const unsigned short* __restrict__ Ab,
                                             const unsigned short* __restrict__ Bb,
                                             int lda, int ldb, int K,
                                             unsigned short* As, unsigned short* Bs,
                                             floatx4 acc[4][4]) {
  const int t = threadIdx.x;
  const int l = t & 63;
  const int w = t >> 6;
  const int wm = w >> 1, wn = w & 1;
  const int sr = t >> 2;            // staging row (0..63, +64 on second issue)
  const int sc = (t & 3) << 3;      // staging k offset (elements)
#pragma unroll
  for (int i = 0; i < 4; ++i)
#pragma unroll
    for (int j = 0; j < 4; ++j) acc[i][j] = (floatx4){0.f, 0.f, 0.f, 0.f};

  const int am = wm * 64 + (l & 15);
  const int bn = wn * 64 + (l & 15);
  const int kq = (l >> 4) << 3;

  for (int k0 = 0; k0 < K; k0 += 32) {
    async16(Ab + (size_t)sr * lda + k0 + sc, As + t * 8);
    async16(Ab + (size_t)(sr + 64) * lda + k0 + sc, As + 2048 + t * 8);
    async16(Bb + (size_t)sr * ldb + k0 + sc, Bs + t * 8);
    async16(Bb + (size_t)(sr + 64) * ldb + k0 + sc, Bs + 2048 + t * 8);
    __syncthreads();
    bf16x8 af[4], bfr[4];
#pragma unroll
    for (int rt = 0; rt < 4; ++rt)
      af[rt] = *(const bf16x8*)(const void*)(As + (am + rt * 16) * 32 + kq);
#pragma unroll
    for (int ct = 0; ct < 4; ++ct)
      bfr[ct] = *(const bf16x8*)(const void*)(Bs + (bn + ct * 16) * 32 + kq);
#pragma unroll
    for (int rt = 0; rt < 4; ++rt)
#pragma unroll
      for (int ct = 0; ct < 4; ++ct)
        acc[rt][ct] = __builtin_amdgcn_mfma_f32_16x16x32_bf16(af[rt], bfr[ct], acc[rt][ct], 0, 0, 0);
    __syncthreads();
  }
}

// ---- K1: projection  Out[bf16] = X(fp32) @ W(fp32)^T + bias ----
// TRANSP=0: Out[m][n] row-major (ld=Hn).  TRANSP=1: Out = Vt[b][n][m] (ld=Sn).
template <int TRANSP>
__global__ __launch_bounds__(256) void k_proj(const float* __restrict__ X,
                                              const float* __restrict__ W,
                                              const float* __restrict__ bias,
                                              unsigned short* __restrict__ Out) {
  __shared__ unsigned short lds[17408];        // 34 KB: staging (2x128x40) or 128x136 transpose buf
  unsigned short* As = lds;
  unsigned short* Bs = lds + 5120;
  const int t = threadIdx.x, l = t & 63, w = t >> 6;
  const int wm = w >> 1, wn = w & 1;
  const int m0 = blockIdx.y * 128, n0 = blockIdx.x * 128;
  floatx4 acc[4][4];
#pragma unroll
  for (int i = 0; i < 4; ++i)
#pragma unroll
    for (int j = 0; j < 4; ++j) acc[i][j] = (floatx4){0.f, 0.f, 0.f, 0.f};

  const int am = wm * 64 + (l & 15), bn = wn * 64 + (l & 15), kq = (l >> 4) << 3;
  const int srow = t >> 3, skg = (t & 7) << 2;

  for (int k0 = 0; k0 < Hn; k0 += 32) {
#pragma unroll
    for (int i = 0; i < 4; ++i) {
      const int row = srow + i * 32;
      float4 va = *(const float4*)(X + (size_t)(m0 + row) * Hn + k0 + skg);
      float4 vb = *(const float4*)(W + (size_t)(n0 + row) * Hn + k0 + skg);
      ushort4 pa = make_ushort4(f2bf(va.x), f2bf(va.y), f2bf(va.z), f2bf(va.w));
      ushort4 pb = make_ushort4(f2bf(vb.x), f2bf(vb.y), f2bf(vb.z), f2bf(vb.w));
      *(ushort4*)(void*)(As + row * 40 + skg) = pa;   // padded stride 40
      *(ushort4*)(void*)(Bs + row * 40 + skg) = pb;
    }
    __syncthreads();
    bf16x8 af[4], bfr[4];
#pragma unroll
    for (int rt = 0; rt < 4; ++rt)
      af[rt] = *(const bf16x8*)(const void*)(As + (am + rt * 16) * 40 + kq);
#pragma unroll
    for (int ct = 0; ct < 4; ++ct)
      bfr[ct] = *(const bf16x8*)(const void*)(Bs + (bn + ct * 16) * 40 + kq);
#pragma unroll
    for (int rt = 0; rt < 4; ++rt)
#pragma unroll
      for (int ct = 0; ct < 4; ++ct)
        acc[rt][ct] = __builtin_amdgcn_mfma_f32_16x16x32_bf16(af[rt], bfr[ct], acc[rt][ct], 0, 0, 0);
    __syncthreads();
  }

  if (TRANSP == 0) {
#pragma unroll
    for (int ct = 0; ct < 4; ++ct) {
      const int col = n0 + wn * 64 + ct * 16 + (l & 15);
      const float bb = bias[col];
#pragma unroll
      for (int rt = 0; rt < 4; ++rt) {
        const int row = m0 + wm * 64 + rt * 16 + ((l >> 4) << 2);
#pragma unroll
        for (int r = 0; r < 4; ++r)
          Out[(size_t)(row + r) * Hn + col] = f2bf(acc[rt][ct][r] + bb);
      }
    }
  } else {
    // write acc into LDS as [n][m] (stride 136), then coalesced store to Vt[b][n][m]
#pragma unroll
    for (int ct = 0; ct < 4; ++ct) {
      const int nl = wn * 64 + ct * 16 + (l & 15);
      const float bb = bias[n0 + nl];
#pragma unroll
      for (int rt = 0; rt < 4; ++rt) {
        const int ml = wm * 64 + rt * 16 + ((l >> 4) << 2);
#pragma unroll
        for (int r = 0; r < 4; ++r) lds[nl * 136 + ml + r] = f2bf(acc[ct == 0 ? rt : rt][ct][r] + bb);
      }
    }
    __syncthreads();
    const int bidx = m0 >> 11;              // batch
    const int mrow = m0 & (Sn - 1);
    unsigned short* Vt = Out + (size_t)bidx * Hn * Sn + mrow;
#pragma unroll
    for (int j = 0; j < 8; ++j) {
      const int e = (j * 256 + t) * 8;
      const int nl = e >> 7, ml = e & 127;
      bf16x8 v = *(const bf16x8*)(const void*)(lds + nl * 136 + ml);
      *(bf16x8*)(void*)(Vt + (size_t)(n0 + nl) * Sn + ml) = v;
    }
  }
}

// ---- K2: scores  Sc[b][q][k] = (Q_b @ K_b^T) / 32, bf16 ----
__global__ __launch_bounds__(256) void k_scores(const unsigned short* __restrict__ Q,
                                                const unsigned short* __restrict__ Kmat,
                                                unsigned short* __restrict__ Sc) {
  __shared__ unsigned short As[128 * 32], Bs[128 * 32];
  const int b = blockIdx.z;
  const int m0 = blockIdx.y * 128, n0 = blockIdx.x * 128;
  const unsigned short* Ab = Q + (size_t)b * Sn * Hn + (size_t)m0 * Hn;
  const unsigned short* Bb = Kmat + (size_t)b * Sn * Hn + (size_t)n0 * Hn;
  floatx4 acc[4][4];
  gemm_bt_main(Ab, Bb, Hn, Hn, Hn, As, Bs, acc);
  const int t = threadIdx.x, l = t & 63, w = t >> 6;
  const int wm = w >> 1, wn = w & 1;
  unsigned short* C = Sc + (size_t)b * Sn * Sn;
#pragma unroll
  for (int ct = 0; ct < 4; ++ct) {
    const int col = n0 + wn * 64 + ct * 16 + (l & 15);
#pragma unroll
    for (int rt = 0; rt < 4; ++rt) {
      const int row = m0 + wm * 64 + rt * 16 + ((l >> 4) << 2);
#pragma unroll
      for (int r = 0; r < 4; ++r)
        C[(size_t)(row + r) * Sn + col] = f2bf(acc[rt][ct][r] * 0.03125f);
    }
  }
}

// ---- K3: masked row softmax over 2048 keys, in-place on Sc; query-mask zeroes row ----
__global__ __launch_bounds__(256) void k_softmax(unsigned short* __restrict__ Sc,
                                                 const int* __restrict__ mask) {
  const int row = blockIdx.x;               // 0..B*S-1
  const int b = row >> 11, q = row & (Sn - 1);
  unsigned short* srow = Sc + (size_t)row * Sn;
  const int* mrow = mask + (size_t)b * Sn;
  const int t = threadIdx.x;
  ushort8v sv = *(const ushort8v*)(const void*)(srow + t * 8);
  int4 mv0 = *(const int4*)(mrow + t * 8);
  int4 mv1 = *(const int4*)(mrow + t * 8 + 4);
  int mk[8] = {mv0.x, mv0.y, mv0.z, mv0.w, mv1.x, mv1.y, mv1.z, mv1.w};
  float s[8];
#pragma unroll
  for (int j = 0; j < 8; ++j) s[j] = mk[j] != 0 ? bf2f(sv[j]) : -1e9f;
  float mx = s[0];
#pragma unroll
  for (int j = 1; j < 8; ++j) mx = fmaxf(mx, s[j]);
#pragma unroll
  for (int off = 32; off; off >>= 1) mx = fmaxf(mx, __shfl_xor(mx, off));
  __shared__ float red[4];
  if ((t & 63) == 0) red[t >> 6] = mx;
  __syncthreads();
  mx = fmaxf(fmaxf(red[0], red[1]), fmaxf(red[2], red[3]));
  float e[8], sum = 0.f;
#pragma unroll
  for (int j = 0; j < 8; ++j) {
    e[j] = __expf(s[j] - mx);   // masked -> exp(-1e9-mx)=0; all-masked -> 1 (matches ref)
    sum += e[j];
  }
#pragma unroll
  for (int off = 32; off; off >>= 1) sum += __shfl_xor(sum, off);
  __syncthreads();
  if ((t & 63) == 0) red[t >> 6] = sum;
  __syncthreads();
  sum = red[0] + red[1] + red[2] + red[3];
  const float inv = (mrow[q] != 0 ? 1.f : 0.f) / sum;  // query mask folded in
  ushort8v ov;
#pragma unroll
  for (int j = 0; j < 8; ++j) ov[j] = f2bf(e[j] * inv);
  *(ushort8v*)(void*)(srow + t * 8) = ov;
}

// ---- K4: Out[b][q][h] = Wt_b @ Vt_b^T, fp32 out ----
__global__ __launch_bounds__(256) void k_out(const unsigned short* __restrict__ Wt,
                                             const unsigned short* __restrict__ Vt,
                                             float* __restrict__ Out) {
  __shared__ unsigned short As[128 * 32], Bs[128 * 32];
  const int b = blockIdx.z;
  const int m0 = blockIdx.y * 128, n0 = blockIdx.x * 128;
  const unsigned short* Ab = Wt + (size_t)b * Sn * Sn + (size_t)m0 * Sn;
  const unsigned short* Bb = Vt + (size_t)b * Hn * Sn + (size_t)n0 * Sn;
  floatx4 acc[4][4];
  gemm_bt_main(Ab, Bb, Sn, Sn, Sn, As, Bs, acc);
  const int t = threadIdx.x, l = t & 63, w = t >> 6;
  const int wm = w >> 1, wn = w & 1;
  float* C = Out + (size_t)b * Sn * Hn;
#pragma unroll
  for (int ct = 0; ct < 4; ++ct) {
    const int col = n0 + wn * 64 + ct * 16 + (l & 15);
#pragma unroll
    for (int rt = 0; rt < 4; ++rt) {
      const int row = m0 + wm * 64 + rt * 16 + ((l >> 4) << 2);
#pragma unroll
      for (int r = 0; r < 4; ++r)
        C[(size_t)(row + r) * Hn + col] = acc[rt][ct][r];
    }
  }
}

extern "C" void kernel_launch(void* const* d_in, const int* in_sizes, int n_in,
                              void* d_out, int out_size, void* d_ws, size_t ws_size,
                              hipStream_t stream) {
  const float* X = (const float*)d_in[0];
  const int* mask = (const int*)d_in[1];
  const float* Wq = (const float*)d_in[2];
  const float* bq = (const float*)d_in[3];
  const float* Wk = (const float*)d_in[4];
  const float* bk = (const float*)d_in[5];
  const float* Wv = (const float*)d_in[6];
  const float* bv = (const float*)d_in[7];
  float* Out = (float*)d_out;

  const size_t NE = (size_t)Bn * Sn * Hn;      // 33,554,432
  unsigned short* Qb = (unsigned short*)d_ws;  // 64 MiB
  unsigned short* Kb = Qb + NE;                // 64 MiB
  unsigned short* Vt = Kb + NE;                // 64 MiB, layout [b][h][s]
  unsigned short* Sc = Vt + NE;                // 128 MiB, layout [b][q][k]

  dim3 blk(256, 1, 1);
  k_proj<0><<<dim3(Hn / 128, (Bn * Sn) / 128, 1), blk, 0, stream>>>(X, Wq, bq, Qb);
  k_proj<0><<<dim3(Hn / 128, (Bn * Sn) / 128, 1), blk, 0, stream>>>(X, Wk, bk, Kb);
  k_proj<1><<<dim3(Hn / 128, (Bn * Sn) / 128, 1), blk, 0, stream>>>(X, Wv, bv, Vt);
  k_scores<<<dim3(Sn / 128, Sn / 128, Bn), blk, 0, stream>>>(Qb, Kb, Sc);
  k_softmax<<<dim3(Bn * Sn, 1, 1), blk, 0, stream>>>(Sc, mask);
  k_out<<<dim3(Hn / 128, Sn / 128, Bn), blk, 0, stream>>>(Sc, Vt, Out);
}

// Round 2
// 935.548 us; speedup vs baseline: 1.2979x; 1.2979x over previous
//
#include <hip/hip_runtime.h>

#define Bn 16
#define Sn 2048
#define Hn 1024

typedef float floatx4 __attribute__((ext_vector_type(4)));
typedef __bf16 bf16x8 __attribute__((ext_vector_type(8)));
typedef unsigned short ushort8v __attribute__((ext_vector_type(8)));

__device__ __forceinline__ unsigned short f2bf(float f) {
  unsigned u = __builtin_bit_cast(unsigned, f);
  u += 0x7FFFu + ((u >> 16) & 1u);  // RNE
  return (unsigned short)(u >> 16);
}
__device__ __forceinline__ float bf2f(unsigned short h) {
  unsigned u = ((unsigned)h) << 16;
  return __builtin_bit_cast(float, u);
}

__device__ __forceinline__ void async16(const unsigned short* g, unsigned short* l) {
  typedef __attribute__((address_space(1))) const unsigned char gu8;
  typedef __attribute__((address_space(3))) unsigned char lu8;
  __builtin_amdgcn_global_load_lds((gu8*)g, (lu8*)l, 16, 0, 0);
}

// ---- bf16 NT GEMM mainloop: C(128x128) = A(128xK) * B(128xK)^T ----
__device__ __forceinline__ void gemm_bt_main(const unsigned short* __restrict__ Ab,
                                             const unsigned short* __restrict__ Bb,
                                             int lda, int ldb, int K,
                                             unsigned short* As, unsigned short* Bs,
                                             floatx4 acc[4][4]) {
  const int t = threadIdx.x;
  const int l = t & 63;
  const int w = t >> 6;
  const int wm = w >> 1, wn = w & 1;
  const int sr = t >> 2;
  const int sc = (t & 3) << 3;
#pragma unroll
  for (int i = 0; i < 4; ++i)
#pragma unroll
    for (int j = 0; j < 4; ++j) acc[i][j] = (floatx4){0.f, 0.f, 0.f, 0.f};

  const int am = wm * 64 + (l & 15);
  const int bn = wn * 64 + (l & 15);
  const int kq = (l >> 4) << 3;

  for (int k0 = 0; k0 < K; k0 += 32) {
    async16(Ab + (size_t)sr * lda + k0 + sc, As + t * 8);
    async16(Ab + (size_t)(sr + 64) * lda + k0 + sc, As + 2048 + t * 8);
    async16(Bb + (size_t)sr * ldb + k0 + sc, Bs + t * 8);
    async16(Bb + (size_t)(sr + 64) * ldb + k0 + sc, Bs + 2048 + t * 8);
    __syncthreads();
    bf16x8 af[4], bfr[4];
#pragma unroll
    for (int rt = 0; rt < 4; ++rt)
      af[rt] = *(const bf16x8*)(const void*)(As + (am + rt * 16) * 32 + kq);
#pragma unroll
    for (int ct = 0; ct < 4; ++ct)
      bfr[ct] = *(const bf16x8*)(const void*)(Bs + (bn + ct * 16) * 32 + kq);
#pragma unroll
    for (int rt = 0; rt < 4; ++rt)
#pragma unroll
      for (int ct = 0; ct < 4; ++ct)
        acc[rt][ct] = __builtin_amdgcn_mfma_f32_16x16x32_bf16(af[rt], bfr[ct], acc[rt][ct], 0, 0, 0);
    __syncthreads();
  }
}

// ---- K0: fp32 -> bf16 conversion of X and the three W matrices ----
// Wb layout: [3][Hn][Hn] (q,k,v concatenated)
__global__ __launch_bounds__(256) void k_cvt(const float* __restrict__ X,
                                             const float* __restrict__ Wq,
                                             const float* __restrict__ Wk,
                                             const float* __restrict__ Wv,
                                             unsigned short* __restrict__ Xb,
                                             unsigned short* __restrict__ Wb) {
  const size_t NX = (size_t)Bn * Sn * Hn;
  const size_t NW = (size_t)Hn * Hn;  // 2^20
  size_t i = ((size_t)blockIdx.x * 256 + threadIdx.x) * 8;
  const float* src;
  unsigned short* dst;
  if (i < NX) {
    src = X + i;
    dst = Xb + i;
  } else {
    size_t j = i - NX;
    int wsel = (int)(j >> 20);
    size_t o = j & (NW - 1);
    src = (wsel == 0 ? Wq : wsel == 1 ? Wk : Wv) + o;
    dst = Wb + j;
  }
  float4 a = *(const float4*)src;
  float4 b = *(const float4*)(src + 4);
  ushort8v o8;
  o8[0] = f2bf(a.x); o8[1] = f2bf(a.y); o8[2] = f2bf(a.z); o8[3] = f2bf(a.w);
  o8[4] = f2bf(b.x); o8[5] = f2bf(b.y); o8[6] = f2bf(b.z); o8[7] = f2bf(b.w);
  *(ushort8v*)(void*)(dst) = o8;
}

// ---- K1: fused QKV projection GEMM (bf16 m97 path) ----
// blockIdx.x: 0..23  -> sel = x>>3 (0=Q,1=K,2=V), n0 = (x&7)*128
// blockIdx.y: m-tile over B*S rows. sel 0/1: row-major out. sel 2: transposed Vt[b][h][s].
__global__ __launch_bounds__(256) void k_projall(const unsigned short* __restrict__ Xb,
                                                 const unsigned short* __restrict__ Wb,
                                                 const float* __restrict__ bq,
                                                 const float* __restrict__ bk,
                                                 const float* __restrict__ bv,
                                                 unsigned short* __restrict__ Qb,
                                                 unsigned short* __restrict__ Kb,
                                                 unsigned short* __restrict__ Vt) {
  __shared__ unsigned short lds[17408];  // union: staging 2x4096 | transpose 128x136
  unsigned short* As = lds;
  unsigned short* Bs = lds + 4096;
  const int sel = blockIdx.x >> 3;
  const int n0 = (blockIdx.x & 7) * 128;
  const int m0 = blockIdx.y * 128;
  const unsigned short* Ab = Xb + (size_t)m0 * Hn;
  const unsigned short* Bb = Wb + (size_t)sel * Hn * Hn + (size_t)n0 * Hn;
  floatx4 acc[4][4];
  gemm_bt_main(Ab, Bb, Hn, Hn, Hn, As, Bs, acc);

  const int t = threadIdx.x, l = t & 63, w = t >> 6;
  const int wm = w >> 1, wn = w & 1;
  const float* bias = sel == 0 ? bq : sel == 1 ? bk : bv;

  if (sel < 2) {
    unsigned short* Out = sel == 0 ? Qb : Kb;
#pragma unroll
    for (int ct = 0; ct < 4; ++ct) {
      const int col = n0 + wn * 64 + ct * 16 + (l & 15);
      const float bb = bias[col];
#pragma unroll
      for (int rt = 0; rt < 4; ++rt) {
        const int row = m0 + wm * 64 + rt * 16 + ((l >> 4) << 2);
#pragma unroll
        for (int r = 0; r < 4; ++r)
          Out[(size_t)(row + r) * Hn + col] = f2bf(acc[rt][ct][r] + bb);
      }
    }
  } else {
    __syncthreads();  // done with staging LDS; reuse as transpose buffer
#pragma unroll
    for (int ct = 0; ct < 4; ++ct) {
      const int nl = wn * 64 + ct * 16 + (l & 15);
      const float bb = bias[n0 + nl];
#pragma unroll
      for (int rt = 0; rt < 4; ++rt) {
        const int ml = wm * 64 + rt * 16 + ((l >> 4) << 2);
#pragma unroll
        for (int r = 0; r < 4; ++r) lds[nl * 136 + ml + r] = f2bf(acc[rt][ct][r] + bb);
      }
    }
    __syncthreads();
    const int bidx = m0 >> 11;
    const int mrow = m0 & (Sn - 1);
    unsigned short* Vp = Vt + (size_t)bidx * Hn * Sn + mrow;
#pragma unroll
    for (int j = 0; j < 8; ++j) {
      const int e = (j * 256 + t) * 8;
      const int nl = e >> 7, ml = e & 127;
      bf16x8 v = *(const bf16x8*)(const void*)(lds + nl * 136 + ml);
      *(bf16x8*)(void*)(Vp + (size_t)(n0 + nl) * Sn + ml) = v;
    }
  }
}

// ---- K2: scores  Sc[b][q][k] = (Q_b @ K_b^T) / 32, bf16 ----
__global__ __launch_bounds__(256) void k_scores(const unsigned short* __restrict__ Q,
                                                const unsigned short* __restrict__ Kmat,
                                                unsigned short* __restrict__ Sc) {
  __shared__ unsigned short As[128 * 32], Bs[128 * 32];
  const int b = blockIdx.z;
  const int m0 = blockIdx.y * 128, n0 = blockIdx.x * 128;
  const unsigned short* Ab = Q + (size_t)b * Sn * Hn + (size_t)m0 * Hn;
  const unsigned short* Bb = Kmat + (size_t)b * Sn * Hn + (size_t)n0 * Hn;
  floatx4 acc[4][4];
  gemm_bt_main(Ab, Bb, Hn, Hn, Hn, As, Bs, acc);
  const int t = threadIdx.x, l = t & 63, w = t >> 6;
  const int wm = w >> 1, wn = w & 1;
  unsigned short* C = Sc + (size_t)b * Sn * Sn;
#pragma unroll
  for (int ct = 0; ct < 4; ++ct) {
    const int col = n0 + wn * 64 + ct * 16 + (l & 15);
#pragma unroll
    for (int rt = 0; rt < 4; ++rt) {
      const int row = m0 + wm * 64 + rt * 16 + ((l >> 4) << 2);
#pragma unroll
      for (int r = 0; r < 4; ++r)
        C[(size_t)(row + r) * Sn + col] = f2bf(acc[rt][ct][r] * 0.03125f);
    }
  }
}

// ---- K3: masked row softmax over 2048 keys, in-place on Sc ----
__global__ __launch_bounds__(256) void k_softmax(unsigned short* __restrict__ Sc,
                                                 const int* __restrict__ mask) {
  const int row = blockIdx.x;
  const int b = row >> 11, q = row & (Sn - 1);
  unsigned short* srow = Sc + (size_t)row * Sn;
  const int* mrow = mask + (size_t)b * Sn;
  const int t = threadIdx.x;
  ushort8v sv = *(const ushort8v*)(const void*)(srow + t * 8);
  int4 mv0 = *(const int4*)(mrow + t * 8);
  int4 mv1 = *(const int4*)(mrow + t * 8 + 4);
  int mk[8] = {mv0.x, mv0.y, mv0.z, mv0.w, mv1.x, mv1.y, mv1.z, mv1.w};
  float s[8];
#pragma unroll
  for (int j = 0; j < 8; ++j) s[j] = mk[j] != 0 ? bf2f(sv[j]) : -1e9f;
  float mx = s[0];
#pragma unroll
  for (int j = 1; j < 8; ++j) mx = fmaxf(mx, s[j]);
#pragma unroll
  for (int off = 32; off; off >>= 1) mx = fmaxf(mx, __shfl_xor(mx, off));
  __shared__ float red[4];
  if ((t & 63) == 0) red[t >> 6] = mx;
  __syncthreads();
  mx = fmaxf(fmaxf(red[0], red[1]), fmaxf(red[2], red[3]));
  float e[8], sum = 0.f;
#pragma unroll
  for (int j = 0; j < 8; ++j) {
    e[j] = __expf(s[j] - mx);
    sum += e[j];
  }
#pragma unroll
  for (int off = 32; off; off >>= 1) sum += __shfl_xor(sum, off);
  __syncthreads();
  if ((t & 63) == 0) red[t >> 6] = sum;
  __syncthreads();
  sum = red[0] + red[1] + red[2] + red[3];
  const float inv = (mrow[q] != 0 ? 1.f : 0.f) / sum;
  ushort8v ov;
#pragma unroll
  for (int j = 0; j < 8; ++j) ov[j] = f2bf(e[j] * inv);
  *(ushort8v*)(void*)(srow + t * 8) = ov;
}

// ---- K4: Out[b][q][h] = Wt_b @ Vt_b^T, fp32 out ----
__global__ __launch_bounds__(256) void k_out(const unsigned short* __restrict__ Wt,
                                             const unsigned short* __restrict__ Vt,
                                             float* __restrict__ Out) {
  __shared__ unsigned short As[128 * 32], Bs[128 * 32];
  const int b = blockIdx.z;
  const int m0 = blockIdx.y * 128, n0 = blockIdx.x * 128;
  const unsigned short* Ab = Wt + (size_t)b * Sn * Sn + (size_t)m0 * Sn;
  const unsigned short* Bb = Vt + (size_t)b * Hn * Sn + (size_t)n0 * Sn;
  floatx4 acc[4][4];
  gemm_bt_main(Ab, Bb, Sn, Sn, Sn, As, Bs, acc);
  const int t = threadIdx.x, l = t & 63, w = t >> 6;
  const int wm = w >> 1, wn = w & 1;
  float* C = Out + (size_t)b * Sn * Hn;
#pragma unroll
  for (int ct = 0; ct < 4; ++ct) {
    const int col = n0 + wn * 64 + ct * 16 + (l & 15);
#pragma unroll
    for (int rt = 0; rt < 4; ++rt) {
      const int row = m0 + wm * 64 + rt * 16 + ((l >> 4) << 2);
#pragma unroll
      for (int r = 0; r < 4; ++r)
        C[(size_t)(row + r) * Hn + col] = acc[rt][ct][r];
    }
  }
}

extern "C" void kernel_launch(void* const* d_in, const int* in_sizes, int n_in,
                              void* d_out, int out_size, void* d_ws, size_t ws_size,
                              hipStream_t stream) {
  const float* X = (const float*)d_in[0];
  const int* mask = (const int*)d_in[1];
  const float* Wq = (const float*)d_in[2];
  const float* bq = (const float*)d_in[3];
  const float* Wk = (const float*)d_in[4];
  const float* bk = (const float*)d_in[5];
  const float* Wv = (const float*)d_in[6];
  const float* bv = (const float*)d_in[7];
  float* Out = (float*)d_out;

  const size_t NE = (size_t)Bn * Sn * Hn;      // 33,554,432
  const size_t NW = (size_t)Hn * Hn;           // 1,048,576
  unsigned short* Qb = (unsigned short*)d_ws;  // 64 MiB
  unsigned short* Kb = Qb + NE;                // 64 MiB
  unsigned short* Vt = Kb + NE;                // 64 MiB, layout [b][h][s]
  unsigned short* Sc = Vt + NE;                // 128 MiB, layout [b][q][k]
  unsigned short* Xb = Sc + (size_t)Bn * Sn * Sn;  // 64 MiB
  unsigned short* Wb = Xb + NE;                // 6 MiB, [3][Hn][Hn]

  dim3 blk(256, 1, 1);
  const int cvt_blocks = (int)((NE + 3 * NW) / 8 / 256);  // 17920
  k_cvt<<<dim3(cvt_blocks, 1, 1), blk, 0, stream>>>(X, Wq, Wk, Wv, Xb, Wb);
  k_projall<<<dim3(24, (Bn * Sn) / 128, 1), blk, 0, stream>>>(Xb, Wb, bq, bk, bv, Qb, Kb, Vt);
  k_scores<<<dim3(Sn / 128, Sn / 128, Bn), blk, 0, stream>>>(Qb, Kb, Sc);
  k_softmax<<<dim3(Bn * Sn, 1, 1), blk, 0, stream>>>(Sc, mask);
  k_out<<<dim3(Hn / 128, Sn / 128, Bn), blk, 0, stream>>>(Sc, Vt, Out);
}